// Round 16
// baseline (112.794 us; speedup 1.0000x reference)
//
#include <hip/hip_runtime.h>
#include <math.h>

#define NB 8
#define N_SRC 2048
#define N_DST 8192
#define C_SRC 128
#define C_SKIP 64
#define C_IN 192
#define C_H 128
#define N_ROWS (NB * N_DST)   /* 65536 */
#define BN_EPS 1e-5f
#define SLOPE 0.01f
#define GEMM_BLOCKS (N_ROWS / 64)   /* 1024 */

using short8 = __attribute__((ext_vector_type(8))) short;
using f32x4  = __attribute__((ext_vector_type(4))) float;
using sf16   = __attribute__((ext_vector_type(16))) float;

static __device__ __forceinline__ unsigned short f2bf(float f) {
    unsigned u = __builtin_bit_cast(unsigned, f);
    u = u + 0x7FFFu + ((u >> 16) & 1u);   // round-to-nearest-even
    return (unsigned short)(u >> 16);
}
static __device__ __forceinline__ float bflo(unsigned v) {
    return __builtin_bit_cast(float, (v & 0xFFFFu) << 16);
}
static __device__ __forceinline__ float bfhi(unsigned v) {
    return __builtin_bit_cast(float, v & 0xFFFF0000u);
}

// ---------------------------------------------------------------------------
// Prep: W1,W2 fp32 -> bf16; pos -> float4 array; pos/batch output copies.
// ---------------------------------------------------------------------------
__global__ __launch_bounds__(256) void k_prep(const float* __restrict__ W1,
                                              unsigned short* __restrict__ W1bf,
                                              const float* __restrict__ W2,
                                              unsigned short* __restrict__ W2bf,
                                              const float* __restrict__ pos,
                                              float4* __restrict__ pos4,
                                              const float* __restrict__ pos_skip,
                                              const int* __restrict__ batch_skip,
                                              float* __restrict__ out_pos,
                                              float* __restrict__ out_batch) {
    int gid = blockIdx.x * 256 + threadIdx.x;
    int stride = gridDim.x * 256;
    for (int i = gid; i < C_H * C_IN; i += stride) W1bf[i] = f2bf(W1[i]);
    for (int i = gid; i < C_H * C_H; i += stride)  W2bf[i] = f2bf(W2[i]);
    for (int p = gid; p < NB * N_SRC; p += stride) {
        pos4[p] = make_float4(pos[p * 3 + 0], pos[p * 3 + 1], pos[p * 3 + 2], 0.f);
    }
    for (int i = gid; i < N_ROWS * 3 / 4; i += stride) {
        ((float4*)out_pos)[i] = ((const float4*)pos_skip)[i];
    }
    for (int i = gid; i < N_ROWS; i += stride) {
        out_batch[i] = (float)batch_skip[i];
    }
}

// ---------------------------------------------------------------------------
// Fused KNN + GEMM1, 512 threads (8 waves). XCD-aware: cloud = blk & 7.
// Scan: verified r14 single-pass s_load_dwordx16 branchy top-3 (best
// measured variant). Merge 24 candidates -> midx/mw. Gather -> bf16 A-tile.
// MFMA1 split over all 8 waves. lrelu; h1 bf16 (or fp32 fallback); BN1
// partials.
// ---------------------------------------------------------------------------
__global__ __launch_bounds__(512, 8) void k_fused1(
    const float4* __restrict__ pos4, const float* __restrict__ pos_skip,
    const float* __restrict__ x, const float* __restrict__ x_skip,
    const unsigned short* __restrict__ Wbf, const float* __restrict__ bias,
    float* __restrict__ out, unsigned short* __restrict__ h1bf,
    float* __restrict__ ps, float* __restrict__ pq) {
    __shared__ __align__(16) unsigned short Ash[64][200];  // 25600 B (overlays)
    __shared__ float sS[4][128];
    __shared__ float sQ[4][128];
    __shared__ int   midx[64][3];
    __shared__ float mw[64][3];

    float* cd = (float*)&Ash[0][0];                  // [8*64*3] floats (6144 B)
    int*   ci = (int*)((char*)&Ash[0][0] + 6144);    // [8*64*3] ints   (6144 B)

    int tid = threadIdx.x;
    int l = tid & 63;
    int v = __builtin_amdgcn_readfirstlane(tid >> 6);  // uniform wave id 0..7
    int blk = blockIdx.x;
    int cloud = blk & 7;                               // XCD-pinned cloud
    int tile  = blk >> 3;
    int r0 = cloud * N_DST + tile * 64;

    // ---------------- scan: 8 waves x 256 points (single-pass) --------------
    int dst = r0 + l;
    float px = pos_skip[dst * 3 + 0];
    float py = pos_skip[dst * 3 + 1];
    float pz = pos_skip[dst * 3 + 2];

    float rr0 = 3.4e38f, rr1 = 3.4e38f, rr2 = 3.4e38f;
    int   ii0 = 0, ii1 = 0, ii2 = 0;

    const char* sp = (const char*)(pos4 + (cloud << 11) + (v << 8));
    for (int g = 0; g < 32; ++g) {           // 32 groups x 8 points
        sf16 A, B;
        asm volatile("s_load_dwordx16 %0, %2, 0x0\n\t"
                     "s_load_dwordx16 %1, %2, 0x40\n\t"
                     "s_waitcnt lgkmcnt(0)"
                     : "=s"(A), "=s"(B)
                     : "s"(sp));
        sp += 128;
        int jb = (v << 8) + g * 8;
#pragma unroll
        for (int k = 0; k < 4; ++k) {
            float dx = px - A[4 * k], dy = py - A[4 * k + 1], dz = pz - A[4 * k + 2];
            float d = fmaf(dx, dx, fmaf(dy, dy, dz * dz));
            if (d < rr2) {
                int jj = jb + k;
                bool c0 = d < rr0, c1 = d < rr1;
                ii2 = c1 ? ii1 : jj;              rr2 = c1 ? rr1 : d;
                ii1 = c1 ? (c0 ? ii0 : jj) : ii1; rr1 = c1 ? (c0 ? rr0 : d) : rr1;
                ii0 = c0 ? jj : ii0;              rr0 = c0 ? d : rr0;
            }
        }
#pragma unroll
        for (int k = 0; k < 4; ++k) {
            float dx = px - B[4 * k], dy = py - B[4 * k + 1], dz = pz - B[4 * k + 2];
            float d = fmaf(dx, dx, fmaf(dy, dy, dz * dz));
            if (d < rr2) {
                int jj = jb + 4 + k;
                bool c0 = d < rr0, c1 = d < rr1;
                ii2 = c1 ? ii1 : jj;              rr2 = c1 ? rr1 : d;
                ii1 = c1 ? (c0 ? ii0 : jj) : ii1; rr1 = c1 ? (c0 ? rr0 : d) : rr1;
                ii0 = c0 ? jj : ii0;              rr0 = c0 ? d : rr0;
            }
        }
    }
    cd[(v * 64 + l) * 3 + 0] = rr0; ci[(v * 64 + l) * 3 + 0] = ii0;
    cd[(v * 64 + l) * 3 + 1] = rr1; ci[(v * 64 + l) * 3 + 1] = ii1;
    cd[(v * 64 + l) * 3 + 2] = rr2; ci[(v * 64 + l) * 3 + 2] = ii2;
    __syncthreads();

    // ---------------- merge 24 candidates per dst ----------------
    if (tid < 64) {
        float e0 = 3.4e38f, e1 = 3.4e38f, e2 = 3.4e38f;
        int   m0 = 0, m1 = 0, m2 = 0;
#pragma unroll
        for (int s = 0; s < 8; ++s) {
#pragma unroll
            for (int t = 0; t < 3; ++t) {
                float d = cd[(s * 64 + tid) * 3 + t];
                int  jj = ci[(s * 64 + tid) * 3 + t];
                if (d < e2) {
                    bool c0 = d < e0, c1 = d < e1;
                    m2 = c1 ? m1 : jj;            e2 = c1 ? e1 : d;
                    m1 = c1 ? (c0 ? m0 : jj) : m1; e1 = c1 ? (c0 ? e0 : d) : e1;
                    m0 = c0 ? jj : m0;            e0 = c0 ? d : e0;
                }
            }
        }
        float w0 = 1.f / fmaxf(e0, 1e-16f);
        float w1 = 1.f / fmaxf(e1, 1e-16f);
        float w2 = 1.f / fmaxf(e2, 1e-16f);
        float inv = 1.f / (w0 + w1 + w2);
        midx[tid][0] = m0; midx[tid][1] = m1; midx[tid][2] = m2;
        mw[tid][0] = w0 * inv; mw[tid][1] = w1 * inv; mw[tid][2] = w2 * inv;
    }
    __syncthreads();

    // ---------------- gather: 8 waves x 8 rows -> bf16 A-tile ----------------
    const float* xb = x + (size_t)cloud * N_SRC * C_SRC;
    for (int rr = v * 8; rr < v * 8 + 8; ++rr) {
        int j0 = midx[rr][0], j1 = midx[rr][1], j2 = midx[rr][2];
        float w0 = mw[rr][0], w1 = mw[rr][1], w2 = mw[rr][2];
        const float2* x0v = (const float2*)(xb + (size_t)j0 * C_SRC);
        const float2* x1v = (const float2*)(xb + (size_t)j1 * C_SRC);
        const float2* x2v = (const float2*)(xb + (size_t)j2 * C_SRC);
        float2 a = x0v[l], b = x1v[l], c = x2v[l];
        float v0 = w0 * a.x + w1 * b.x + w2 * c.x;
        float v1 = w0 * a.y + w1 * b.y + w2 * c.y;
        ((unsigned*)&Ash[rr][0])[l] = (unsigned)f2bf(v0) | ((unsigned)f2bf(v1) << 16);
        Ash[rr][128 + l] = f2bf(x_skip[(size_t)(r0 + rr) * C_SKIP + l]);
    }
    __syncthreads();

    // ---------------- MFMA1: all 8 waves ----------------
    int wr = v & 3, wc = v >> 2;           // uniform
    int cl = l & 15, kh = l >> 4;
    f32x4 acc[4];
#pragma unroll
    for (int n = 0; n < 4; ++n) {
        float bv = bias[wc * 64 + n * 16 + cl];
        acc[n][0] = bv; acc[n][1] = bv; acc[n][2] = bv; acc[n][3] = bv;
    }
    const unsigned short* wb = Wbf + (size_t)(wc * 4) * 16 * C_IN +
                               (size_t)cl * C_IN + kh * 8;
    for (int kt = 0; kt < 6; ++kt) {
        short8 af = *(const short8*)&Ash[wr * 16 + cl][kt * 32 + kh * 8];
#pragma unroll
        for (int n = 0; n < 4; ++n) {
            short8 bf = *(const short8*)(wb + (size_t)n * 16 * C_IN + kt * 32);
            acc[n] = __builtin_amdgcn_mfma_f32_16x16x32_bf16(af, bf, acc[n], 0, 0, 0);
        }
    }

    // ---------------- lrelu + BN1 partials ----------------
    float pss[4], pqs[4];
#pragma unroll
    for (int n = 0; n < 4; ++n) {
        float s = 0.f, q = 0.f;
#pragma unroll
        for (int j = 0; j < 4; ++j) {
            float z = acc[n][j];
            z = z > 0.f ? z : SLOPE * z;
            acc[n][j] = z;
            s += z; q += z * z;
        }
        s += __shfl_xor(s, 16); s += __shfl_xor(s, 32);
        q += __shfl_xor(q, 16); q += __shfl_xor(q, 32);
        pss[n] = s; pqs[n] = q;
    }

    __syncthreads();     // all Ash MFMA reads complete before overwrite
    if (l < 16) {
#pragma unroll
        for (int n = 0; n < 4; ++n) {
            sS[wr][wc * 64 + n * 16 + l] = pss[n];
            sQ[wr][wc * 64 + n * 16 + l] = pqs[n];
        }
    }
    if (h1bf) {
        unsigned short* Az = (unsigned short*)&Ash[0][0];   // packed [64][128]
#pragma unroll
        for (int n = 0; n < 4; ++n) {
            int col = wc * 64 + n * 16 + cl;
#pragma unroll
            for (int j = 0; j < 4; ++j) {
                Az[(wr * 16 + kh * 4 + j) * 128 + col] = f2bf(acc[n][j]);
            }
        }
    } else {
#pragma unroll
        for (int n = 0; n < 4; ++n) {
            int col = wc * 64 + n * 16 + cl;
#pragma unroll
            for (int j = 0; j < 4; ++j) {
                out[(size_t)(r0 + wr * 16 + kh * 4 + j) * C_H + col] = acc[n][j];
            }
        }
    }
    __syncthreads();
    if (h1bf) {
        const uint4* Asrc = (const uint4*)&Ash[0][0];
        uint4* zdst = (uint4*)(h1bf + (size_t)r0 * C_H);
        for (int i = tid; i < 64 * C_H / 8; i += 512) zdst[i] = Asrc[i];
    }
    if (tid < 128) {
        float s = sS[0][tid] + sS[1][tid] + sS[2][tid] + sS[3][tid];
        float q = sQ[0][tid] + sQ[1][tid] + sQ[2][tid] + sQ[3][tid];
        ps[blk * C_H + tid] = s;
        pq[blk * C_H + tid] = q;
    }
}

// ---------------------------------------------------------------------------
// Per-channel reduce of block partials -> BN affine
// ---------------------------------------------------------------------------
__global__ __launch_bounds__(256) void k_reduce(const float* __restrict__ ps,
                                                const float* __restrict__ pq,
                                                const float* __restrict__ g,
                                                const float* __restrict__ be,
                                                float* __restrict__ a_out,
                                                float* __restrict__ c_out) {
    int col = blockIdx.x;
    float s = 0.f, q = 0.f;
    for (int b = threadIdx.x; b < GEMM_BLOCKS; b += 256) {
        s += ps[b * C_H + col];
        q += pq[b * C_H + col];
    }
    for (int off = 32; off; off >>= 1) {
        s += __shfl_down(s, off);
        q += __shfl_down(q, off);
    }
    __shared__ float rs[4], rq[4];
    if ((threadIdx.x & 63) == 0) { rs[threadIdx.x >> 6] = s; rq[threadIdx.x >> 6] = q; }
    __syncthreads();
    if (threadIdx.x == 0) {
        s = rs[0] + rs[1] + rs[2] + rs[3];
        q = rq[0] + rq[1] + rq[2] + rq[3];
        float mean = s / (float)N_ROWS;
        float var  = q / (float)N_ROWS - mean * mean;
        float a = g[col] * rsqrtf(var + BN_EPS);
        a_out[col] = a;
        c_out[col] = be[col] - mean * a;
    }
}

// ---------------------------------------------------------------------------
// GEMM2a, 512 threads (8 waves): stage Ash = bf16(a1*h1 + c1) from h1bf
// (bf16) or h (fp32); MFMA2 split over 8 waves (wave v = (wr,wc), acc[4]);
// lrelu; BN2 partials; stash lrelu(z2) bf16 IN PLACE over h1bf (use_z).
// ---------------------------------------------------------------------------
__global__ __launch_bounds__(512, 8) void k_g2a(const float* __restrict__ h,
                                                unsigned short* __restrict__ h1bf,
                                                const unsigned short* __restrict__ Wbf,
                                                const float* __restrict__ b2,
                                                const float* __restrict__ a1,
                                                const float* __restrict__ c1,
                                                float* __restrict__ ps,
                                                float* __restrict__ pq) {
    __shared__ __align__(16) unsigned short Ash[64][136];
    __shared__ float sS[4][128];
    __shared__ float sQ[4][128];

    int r0 = blockIdx.x * 64;
    int tid = threadIdx.x;
    int l = tid & 63;
    int v = __builtin_amdgcn_readfirstlane(tid >> 6);

    if (h1bf) {
        const uint4* src = (const uint4*)(h1bf + (size_t)r0 * C_H);
        for (int i = tid; i < 64 * C_H / 8; i += 512) {
            uint4 vv = src[i];
            int c0 = (i * 8) & 127, r = (i * 8) >> 7;
            float4 a0 = *(const float4*)&a1[c0];
            float4 a4 = *(const float4*)&a1[c0 + 4];
            float4 c0v = *(const float4*)&c1[c0];
            float4 c4v = *(const float4*)&c1[c0 + 4];
            unsigned o0 = (unsigned)f2bf(fmaf(a0.x, bflo(vv.x), c0v.x)) |
                          ((unsigned)f2bf(fmaf(a0.y, bfhi(vv.x), c0v.y)) << 16);
            unsigned o1 = (unsigned)f2bf(fmaf(a0.z, bflo(vv.y), c0v.z)) |
                          ((unsigned)f2bf(fmaf(a0.w, bfhi(vv.y), c0v.w)) << 16);
            unsigned o2 = (unsigned)f2bf(fmaf(a4.x, bflo(vv.z), c4v.x)) |
                          ((unsigned)f2bf(fmaf(a4.y, bfhi(vv.z), c4v.y)) << 16);
            unsigned o3 = (unsigned)f2bf(fmaf(a4.z, bflo(vv.w), c4v.z)) |
                          ((unsigned)f2bf(fmaf(a4.w, bfhi(vv.w), c4v.w)) << 16);
            *(uint4*)&Ash[r][c0] = make_uint4(o0, o1, o2, o3);
        }
    } else {
        const float* src = h + (size_t)r0 * C_H;
        for (int i = tid * 4; i < 64 * C_H; i += 2048) {
            float4 vf = *(const float4*)&src[i];
            int r = i >> 7, c = i & 127;
            float4 av = *(const float4*)&a1[c];
            float4 cv = *(const float4*)&c1[c];
            unsigned lo = (unsigned)f2bf(fmaf(av.x, vf.x, cv.x)) |
                          ((unsigned)f2bf(fmaf(av.y, vf.y, cv.y)) << 16);
            unsigned hi = (unsigned)f2bf(fmaf(av.z, vf.z, cv.z)) |
                          ((unsigned)f2bf(fmaf(av.w, vf.w, cv.w)) << 16);
            *(uint2*)&Ash[r][c] = make_uint2(lo, hi);
        }
    }
    __syncthreads();

    int wr = v & 3, wc = v >> 2;           // uniform
    int cl = l & 15, kh = l >> 4;
    f32x4 acc[4];
#pragma unroll
    for (int n = 0; n < 4; ++n) {
        float bv = b2[wc * 64 + n * 16 + cl];
        acc[n][0] = bv; acc[n][1] = bv; acc[n][2] = bv; acc[n][3] = bv;
    }
    const unsigned short* wb = Wbf + (size_t)(wc * 4) * 16 * C_H +
                               (size_t)cl * C_H + kh * 8;
    for (int kt = 0; kt < 4; ++kt) {
        short8 af = *(const short8*)&Ash[wr * 16 + cl][kt * 32 + kh * 8];
#pragma unroll
        for (int n = 0; n < 4; ++n) {
            short8 bf = *(const short8*)(wb + (size_t)n * 16 * C_H + kt * 32);
            acc[n] = __builtin_amdgcn_mfma_f32_16x16x32_bf16(af, bf, acc[n], 0, 0, 0);
        }
    }

    float pss[4], pqs[4];
#pragma unroll
    for (int n = 0; n < 4; ++n) {
        float s = 0.f, q = 0.f;
#pragma unroll
        for (int j = 0; j < 4; ++j) {
            float z = acc[n][j];
            z = z > 0.f ? z : SLOPE * z;
            acc[n][j] = z;                // keep lrelu'd z2
            s += z; q += z * z;
        }
        s += __shfl_xor(s, 16); s += __shfl_xor(s, 32);
        q += __shfl_xor(q, 16); q += __shfl_xor(q, 32);
        pss[n] = s; pqs[n] = q;
    }

    __syncthreads();                      // all Ash k-loop reads complete
    if (l < 16) {
#pragma unroll
        for (int n = 0; n < 4; ++n) {
            sS[wr][wc * 64 + n * 16 + l] = pss[n];
            sQ[wr][wc * 64 + n * 16 + l] = pqs[n];
        }
    }
    if (h1bf) {
        unsigned short* Az = (unsigned short*)&Ash[0][0];   // packed [64][128]
#pragma unroll
        for (int n = 0; n < 4; ++n) {
            int col = wc * 64 + n * 16 + cl;
#pragma unroll
            for (int j = 0; j < 4; ++j) {
                Az[(wr * 16 + kh * 4 + j) * 128 + col] = f2bf(acc[n][j]);
            }
        }
    }
    __syncthreads();
    if (h1bf) {
        const uint4* Asrc = (const uint4*)&Ash[0][0];
        uint4* zdst = (uint4*)(h1bf + (size_t)r0 * C_H);
        for (int i = tid; i < 64 * C_H / 8; i += 512) zdst[i] = Asrc[i];
    }
    if (tid < 128) {
        float s = sS[0][tid] + sS[1][tid] + sS[2][tid] + sS[3][tid];
        float q = sQ[0][tid] + sQ[1][tid] + sQ[2][tid] + sQ[3][tid];
        ps[blockIdx.x * C_H + tid] = s;
        pq[blockIdx.x * C_H + tid] = q;
    }
}

// ---------------------------------------------------------------------------
// Final (use_z): out_h = a2 * z2bf + c2, elementwise, fully coalesced.
// ---------------------------------------------------------------------------
__global__ __launch_bounds__(256) void k_final(const unsigned short* __restrict__ z2bf,
                                               const float* __restrict__ a2,
                                               const float* __restrict__ c2,
                                               float* __restrict__ out_h) {
    __shared__ float sa[128], sc[128];
    int tid = threadIdx.x;
    if (tid < 128) { sa[tid] = a2[tid]; sc[tid] = c2[tid]; }
    __syncthreads();

    int gid = blockIdx.x * 256 + tid;
    int stride = gridDim.x * 256;
    const uint4* zsrc = (const uint4*)z2bf;
    for (int i = gid; i < N_ROWS * C_H / 8; i += stride) {
        uint4 v = zsrc[i];
        int c0 = (i * 8) & 127;
        float4 o0, o1;
        o0.x = fmaf(sa[c0 + 0], bflo(v.x), sc[c0 + 0]);
        o0.y = fmaf(sa[c0 + 1], bfhi(v.x), sc[c0 + 1]);
        o0.z = fmaf(sa[c0 + 2], bflo(v.y), sc[c0 + 2]);
        o0.w = fmaf(sa[c0 + 3], bfhi(v.y), sc[c0 + 3]);
        o1.x = fmaf(sa[c0 + 4], bflo(v.z), sc[c0 + 4]);
        o1.y = fmaf(sa[c0 + 5], bfhi(v.z), sc[c0 + 5]);
        o1.z = fmaf(sa[c0 + 6], bflo(v.w), sc[c0 + 6]);
        o1.w = fmaf(sa[c0 + 7], bfhi(v.w), sc[c0 + 7]);
        *(float4*)&out_h[(size_t)i * 8]     = o0;
        *(float4*)&out_h[(size_t)i * 8 + 4] = o1;
    }
}

// ---------------------------------------------------------------------------
// GEMM2b (fallback, !use_z): recompute z2 from fp32 h1 in d_out, lrelu +
// BN2 affine, in-place write.
// ---------------------------------------------------------------------------
__global__ __launch_bounds__(256) void k_g2b(float* __restrict__ h,
                                             const unsigned short* __restrict__ Wbf,
                                             const float* __restrict__ b2,
                                             const float* __restrict__ a1,
                                             const float* __restrict__ c1,
                                             const float* __restrict__ a2,
                                             const float* __restrict__ c2) {
    __shared__ __align__(16) unsigned short Ash[64][136];

    int r0 = blockIdx.x * 64;
    int tid = threadIdx.x;
    int l = tid & 63, w = tid >> 6;

    const float* src = h + (size_t)r0 * C_H;
    for (int i = tid * 4; i < 64 * C_H; i += 1024) {
        float4 vf = *(const float4*)&src[i];
        int r = i >> 7, c = i & 127;
        float4 av = *(const float4*)&a1[c];
        float4 cv = *(const float4*)&c1[c];
        unsigned lo = (unsigned)f2bf(fmaf(av.x, vf.x, cv.x)) |
                      ((unsigned)f2bf(fmaf(av.y, vf.y, cv.y)) << 16);
        unsigned hi = (unsigned)f2bf(fmaf(av.z, vf.z, cv.z)) |
                      ((unsigned)f2bf(fmaf(av.w, vf.w, cv.w)) << 16);
        *(uint2*)&Ash[r][c] = make_uint2(lo, hi);
    }
    __syncthreads();

    int cl = l & 15, kh = l >> 4;
    f32x4 acc[8];
#pragma unroll
    for (int n = 0; n < 8; ++n) {
        float bv = b2[n * 16 + cl];
        acc[n][0] = bv; acc[n][1] = bv; acc[n][2] = bv; acc[n][3] = bv;
    }
    const unsigned short* wb = Wbf + (size_t)cl * C_H + kh * 8;
    for (int kt = 0; kt < 4; ++kt) {
        short8 af = *(const short8*)&Ash[w * 16 + cl][kt * 32 + kh * 8];
#pragma unroll
        for (int n = 0; n < 8; ++n) {
            short8 bf = *(const short8*)(wb + (size_t)n * 16 * C_H + kt * 32);
            acc[n] = __builtin_amdgcn_mfma_f32_16x16x32_bf16(af, bf, acc[n], 0, 0, 0);
        }
    }

#pragma unroll
    for (int n = 0; n < 8; ++n) {
        int col = n * 16 + cl;
        float av = a2[col], cv = c2[col];
#pragma unroll
        for (int j = 0; j < 4; ++j) {
            int row = r0 + w * 16 + kh * 4 + j;
            float z = acc[n][j];
            z = z > 0.f ? z : SLOPE * z;
            h[(size_t)row * C_H + col] = av * z + cv;
        }
    }
}

// ---------------------------------------------------------------------------
extern "C" void kernel_launch(void* const* d_in, const int* in_sizes, int n_in,
                              void* d_out, int out_size, void* d_ws, size_t ws_size,
                              hipStream_t stream) {
    const float* x          = (const float*)d_in[0];
    const float* pos        = (const float*)d_in[1];
    const float* x_skip     = (const float*)d_in[3];
    const float* pos_skip   = (const float*)d_in[4];
    const int*   batch_skip = (const int*)d_in[5];
    const float* W1  = (const float*)d_in[6];
    const float* b1  = (const float*)d_in[7];
    const float* g1  = (const float*)d_in[8];
    const float* be1 = (const float*)d_in[9];
    const float* W2  = (const float*)d_in[10];
    const float* b2  = (const float*)d_in[11];
    const float* g2  = (const float*)d_in[12];
    const float* be2 = (const float*)d_in[13];

    float* out_h     = (float*)d_out;
    float* out_pos   = out_h + (size_t)N_ROWS * C_H;
    float* out_batch = out_pos + (size_t)N_ROWS * 3;

    float* wsf = (float*)d_ws;
    float4* pos4         = (float4*)wsf;                         // 65536 floats
    unsigned short* W1bf = (unsigned short*)(wsf + 65536);       // 24576 us
    unsigned short* W2bf = (unsigned short*)(wsf + 77824);       // 16384 us
    float* p1s = wsf + 86016;                                    // 131072
    float* p1q = p1s + 131072;
    float* p2s = p1q + 131072;
    float* p2q = p2s + 131072;
    float* a1g = p2q + 131072;
    float* c1g = a1g + 128;
    float* a2g = c1g + 128;
    float* c2g = a2g + 128;
    unsigned short* zbuf = (unsigned short*)(c2g + 128);         // 8388608 us
    size_t ws_needed = ((size_t)610816 * 4) + (size_t)N_ROWS * C_H * 2;
    bool use_z = ws_size >= ws_needed;
    unsigned short* h1bf = use_z ? zbuf : (unsigned short*)nullptr;

    k_prep<<<256, 256, 0, stream>>>(W1, W1bf, W2, W2bf, pos, pos4,
                                    pos_skip, batch_skip, out_pos, out_batch);
    k_fused1<<<GEMM_BLOCKS, 512, 0, stream>>>(pos4, pos_skip, x, x_skip, W1bf, b1,
                                              out_h, h1bf, p1s, p1q);
    k_reduce<<<C_H, 256, 0, stream>>>(p1s, p1q, g1, be1, a1g, c1g);
    k_g2a<<<GEMM_BLOCKS, 512, 0, stream>>>(out_h, h1bf, W2bf, b2, a1g, c1g,
                                           p2s, p2q);
    k_reduce<<<C_H, 256, 0, stream>>>(p2s, p2q, g2, be2, a2g, c2g);
    if (use_z) {
        k_final<<<1024, 256, 0, stream>>>(zbuf, a2g, c2g, out_h);
    } else {
        k_g2b<<<GEMM_BLOCKS, 256, 0, stream>>>(out_h, W2bf, b2, a1g, c1g, a2g, c2g);
    }
}